// Round 2
// baseline (549.963 us; speedup 1.0000x reference)
//
#include <hip/hip_runtime.h>
#include <math.h>

namespace {
constexpr int   BS_   = 64;
constexpr int   D_    = 768;
constexpr int   NVL_  = 192;            // 3*BS rows of vl_embeddings
constexpr int   NQ_   = 128;            // query rows (vl[64:])
constexpr int   CAP_  = 131072;
constexpr int   NCOL_ = NVL_ + CAP_;    // 131264
constexpr float THR_  = 0.5f;
constexpr float EPS_  = 1e-8f;

// workspace float offsets
constexpr int WS_QN  = 0;    // 128 query norms
constexpr int WS_SL  = 128;  // 1   global label sum
constexpr int WS_MN  = 160;  // 128 per-row min(sim_m)
constexpr int WS_MX  = 288;  // 128 per-row max(sim_m)
constexpr int WS_SS  = 416;  // 128 per-row sum(sim_m + 1)
constexpr int WS_SSL = 544;  // 128 per-row sum((sim_m + 1)*label)
constexpr int WS_S0  = 672;  // 128 per-row sum(sim where selected)
constexpr int WS_CNT = 800;  // 128 per-row count(selected)

constexpr int KC    = 32;    // K chunk
constexpr int TN    = 128;   // columns per block
constexpr int PITCH = 132;   // LDS row pitch (16B-aligned rows, de-conflicted)
}

__device__ inline void atomicMinF(float* addr, float v) {
    if (v >= 0.f) atomicMin((int*)addr, __float_as_int(v));
    else          atomicMax((unsigned int*)addr, __float_as_uint(v));
}
__device__ inline void atomicMaxF(float* addr, float v) {
    if (v >= 0.f) atomicMax((int*)addr, __float_as_int(v));
    else          atomicMin((unsigned int*)addr, __float_as_uint(v));
}

// ---------------- kernel 0: init accumulators ----------------
__global__ void lpe_init(float* ws) {
    int t = threadIdx.x;
    if (t < NQ_) {
        ws[WS_MN + t]  = INFINITY;
        ws[WS_MX + t]  = -INFINITY;
        ws[WS_SS + t]  = 0.f;
        ws[WS_SSL + t] = 0.f;
        ws[WS_S0 + t]  = 0.f;
        ws[WS_CNT + t] = 0.f;
    }
    if (t == 0) ws[WS_SL] = 0.f;
}

// ---------------- kernel 1: query norms + global label sum ----------------
__global__ void lpe_prep(const float* __restrict__ vl,
                         const float* __restrict__ itm,
                         const float* __restrict__ expl,
                         float* ws) {
    __shared__ float red[256];
    int b = blockIdx.x, t = threadIdx.x;
    if (b < NQ_) {
        const float* row = vl + (size_t)(BS_ + b) * D_;
        float s = 0.f;
        for (int k = t; k < D_; k += 256) { float v = row[k]; s += v * v; }
        red[t] = s; __syncthreads();
        for (int o = 128; o > 0; o >>= 1) { if (t < o) red[t] += red[t + o]; __syncthreads(); }
        if (t == 0) ws[WS_QN + b] = sqrtf(red[0]);
    } else {
        int idx = (b - NQ_) * 256 + t;
        float s = 0.f;
        for (int j = idx; j < NCOL_; j += 256 * 256)
            s += (j < NVL_) ? itm[j] : expl[j - NVL_];
        red[t] = s; __syncthreads();
        for (int o = 128; o > 0; o >>= 1) { if (t < o) red[t] += red[t + o]; __syncthreads(); }
        if (t == 0) atomicAdd(ws + WS_SL, red[0]);
    }
}

// ---------------- kernel 2: fused GEMM + column stats + row reductions ----------------
__global__ __launch_bounds__(256) void lpe_main(
        const float* __restrict__ vl, const float* __restrict__ score,
        const float* __restrict__ itm, const float* __restrict__ queue,
        const float* __restrict__ expl, const float* __restrict__ W,
        const float* __restrict__ bvec, float* ws) {
    __shared__ float qs[KC][PITCH];    // q^T chunk: qs[k][row]
    __shared__ float cs[KC][PITCH];    // col chunk: cs[k][col]
    __shared__ float colnorm[TN], colscore[TN], collab[TN];
    __shared__ float rowscore[NQ_], qn_s[NQ_];

    const int t   = threadIdx.x;
    const int tx  = t & 15;       // col group
    const int ty  = t >> 4;       // row group
    const int col0 = blockIdx.x * TN;

    if (t < NQ_) { rowscore[t] = score[BS_ + t]; qn_s[t] = ws[WS_QN + t]; }
    if (t < TN) {
        int j = col0 + t;
        float lab = 0.f;
        if (j < NCOL_) lab = (j < NVL_) ? itm[j] : expl[j - NVL_];
        collab[t] = lab;
    }
    const float b0 = bvec[0], b1 = bvec[1];

    float acc[8][8];
#pragma unroll
    for (int u = 0; u < 8; ++u)
#pragma unroll
        for (int v = 0; v < 8; ++v) acc[u][v] = 0.f;

    float c_ss[4] = {0.f, 0.f, 0.f, 0.f};
    float c_z0[4] = {0.f, 0.f, 0.f, 0.f};
    float c_z1[4] = {0.f, 0.f, 0.f, 0.f};

    for (int k0 = 0; k0 < D_; k0 += KC) {
        __syncthreads();
        // stage q tile (all blocks read same 128x768 region; L2-resident)
#pragma unroll
        for (int p = 0; p < 4; ++p) {
            int id = t + p * 256;
            int r = id >> 3, kg = id & 7;
            const float4 v = *(const float4*)(vl + (size_t)(BS_ + r) * D_ + k0 + kg * 4);
            qs[kg * 4 + 0][r] = v.x; qs[kg * 4 + 1][r] = v.y;
            qs[kg * 4 + 2][r] = v.z; qs[kg * 4 + 3][r] = v.w;
        }
        // stage column tile + accumulate per-column stats from loaded regs
#pragma unroll
        for (int p = 0; p < 4; ++p) {
            int id = t + p * 256;
            int c = id >> 3, kg = id & 7;
            int j = col0 + c;
            float4 v = make_float4(0.f, 0.f, 0.f, 0.f);
            if (j < NCOL_) {
                const float* src = (j < NVL_) ? (vl + (size_t)j * D_)
                                              : (queue + (size_t)(j - NVL_) * D_);
                v = *(const float4*)(src + k0 + kg * 4);
            }
            int k = k0 + kg * 4;
            const float4 w01 = *(const float4*)(W + k * 2);       // W0[k],W1[k],W0[k+1],W1[k+1]
            const float4 w23 = *(const float4*)(W + k * 2 + 4);
            c_ss[p] += v.x * v.x + v.y * v.y + v.z * v.z + v.w * v.w;
            c_z0[p] += v.x * w01.x + v.y * w01.z + v.z * w23.x + v.w * w23.z;
            c_z1[p] += v.x * w01.y + v.y * w01.w + v.z * w23.y + v.w * w23.w;
            cs[kg * 4 + 0][c] = v.x; cs[kg * 4 + 1][c] = v.y;
            cs[kg * 4 + 2][c] = v.z; cs[kg * 4 + 3][c] = v.w;
        }
        __syncthreads();
#pragma unroll 4
        for (int k = 0; k < KC; ++k) {
            float a[8] __attribute__((aligned(16)));
            float bb[8] __attribute__((aligned(16)));
            *(float4*)(a)      = *(const float4*)(&qs[k][ty * 8]);
            *(float4*)(a + 4)  = *(const float4*)(&qs[k][ty * 8 + 4]);
            *(float4*)(bb)     = *(const float4*)(&cs[k][tx * 8]);
            *(float4*)(bb + 4) = *(const float4*)(&cs[k][tx * 8 + 4]);
#pragma unroll
            for (int u = 0; u < 8; ++u)
#pragma unroll
                for (int v = 0; v < 8; ++v)
                    acc[u][v] = fmaf(a[u], bb[v], acc[u][v]);
        }
    }

    // finalize per-column stats: reduce over the 8 lanes (k-slices) sharing a column
#pragma unroll
    for (int p = 0; p < 4; ++p) {
#pragma unroll
        for (int off = 1; off < 8; off <<= 1) {
            c_ss[p] += __shfl_xor(c_ss[p], off);
            c_z0[p] += __shfl_xor(c_z0[p], off);
            c_z1[p] += __shfl_xor(c_z1[p], off);
        }
    }
    if ((t & 7) == 0) {
#pragma unroll
        for (int p = 0; p < 4; ++p) {
            int c = (t >> 3) + 32 * p;
            int j = col0 + c;
            colnorm[c] = sqrtf(c_ss[p]);
            float sc;
            if (j < NVL_) sc = (j < NCOL_) ? score[j] : 0.f;
            else { float z = (c_z1[p] + b1) - (c_z0[p] + b0); sc = 1.f / (1.f + expf(-z)); }
            colscore[c] = sc;
        }
    }
    __syncthreads();

    // epilogue: per-row online reductions
#pragma unroll
    for (int u = 0; u < 8; ++u) {
        const int r = ty * 8 + u;
        const float qn = qn_s[r];
        const float rs = rowscore[r];
        float mn = INFINITY, mx = -INFINITY, ssP = 0.f, sslP = 0.f, s0 = 0.f, cnt = 0.f;
#pragma unroll
        for (int v = 0; v < 8; ++v) {
            int c = tx * 8 + v;
            int j = col0 + c;
            if (j >= NCOL_) continue;
            float cosv = acc[u][v] / fmaxf(qn * colnorm[c], EPS_);
            float dd = colscore[c] - rs; dd = dd * dd;
            float sim = cosv * (1.f - dd);
            bool sel = (cosv >= THR_);
            float sim_m = sel ? sim : -1.f;
            mn = fminf(mn, sim_m);
            mx = fmaxf(mx, sim_m);
            ssP  += sim_m + 1.f;
            sslP += (sim_m + 1.f) * collab[c];
            if (sel) { s0 += sim; cnt += 1.f; }
        }
        // reduce across the 16 lanes (tx) sharing this row
#pragma unroll
        for (int off = 1; off < 16; off <<= 1) {
            mn = fminf(mn, __shfl_xor(mn, off));
            mx = fmaxf(mx, __shfl_xor(mx, off));
            ssP  += __shfl_xor(ssP, off);
            sslP += __shfl_xor(sslP, off);
            s0   += __shfl_xor(s0, off);
            cnt  += __shfl_xor(cnt, off);
        }
        if (tx == 0) {
            atomicMinF(ws + WS_MN + r, mn);
            atomicMaxF(ws + WS_MX + r, mx);
            atomicAdd(ws + WS_SS + r, ssP);
            atomicAdd(ws + WS_SSL + r, sslP);
            atomicAdd(ws + WS_S0 + r, s0);
            atomicAdd(ws + WS_CNT + r, cnt);
        }
    }
}

// ---------------- kernel 3: finalize outputs ----------------
__global__ void lpe_final(float* out, const float* ws) {
    int t = threadIdx.x;
    if (t < BS_) {
        out[t] = 1.f;            // exp_itm_label[:64]
        out[192 + t] = 1.f;      // exp_wo_alter_label[:64]
        out[385 + t] = 0.f;      // weights[:64]
    }
    if (t == 0) out[384] = 1.0f; // gamma = 131264/131264
    if (t >= BS_ && t < NVL_) {
        int i = t - BS_;
        float mn   = ws[WS_MN + i],  mx   = ws[WS_MX + i];
        float ssP  = ws[WS_SS + i],  sslP = ws[WS_SSL + i];
        float s0   = ws[WS_S0 + i],  cnt  = ws[WS_CNT + i];
        float Sl   = ws[WS_SL];
        float denomA = mx - mn + 1e-8f;
        float shift  = mn + 1.f;            // == 0 when min is the -1 sentinel
        float sumd = (ssP - (float)NCOL_ * shift) / denomA;
        float num  = (sslP - shift * Sl) / denomA;
        float wo   = num / (sumd + 1e-8f);
        float alt  = fmaxf(wo, 0.f);
        float w    = (cnt != 0.f) ? s0 / fmaxf(cnt, 1.f) : 0.f;
        float wt   = fmaxf(w - THR_, 0.f) / (1.f - THR_);
        out[BS_ + i] = alt;          // exp_itm_label[64:]
        out[192 + BS_ + i] = wo;     // exp_wo_alter_label[64:]
        out[385 + BS_ + i] = wt;     // weights[64:]
    }
}

extern "C" void kernel_launch(void* const* d_in, const int* in_sizes, int n_in,
                              void* d_out, int out_size, void* d_ws, size_t ws_size,
                              hipStream_t stream) {
    const float* vl    = (const float*)d_in[0];
    const float* score = (const float*)d_in[1];
    const float* itm   = (const float*)d_in[2];
    const float* queue = (const float*)d_in[3];
    const float* expl  = (const float*)d_in[4];
    const float* W     = (const float*)d_in[5];
    const float* b     = (const float*)d_in[6];
    float* out = (float*)d_out;
    float* ws  = (float*)d_ws;

    lpe_init<<<1, 256, 0, stream>>>(ws);
    lpe_prep<<<NQ_ + 256, 256, 0, stream>>>(vl, itm, expl, ws);
    const int nblk = (NCOL_ + TN - 1) / TN;   // 1026
    lpe_main<<<nblk, 256, 0, stream>>>(vl, score, itm, queue, expl, W, b, ws);
    lpe_final<<<1, 256, 0, stream>>>(out, ws);
}

// Round 3
// 279.268 us; speedup vs baseline: 1.9693x; 1.9693x over previous
//
#include <hip/hip_runtime.h>
#include <math.h>

namespace {
constexpr int   BS_   = 64;
constexpr int   D_    = 768;
constexpr int   NVL_  = 192;            // 3*BS rows of vl_embeddings
constexpr int   NQ_   = 128;            // query rows (vl[64:])
constexpr int   CAP_  = 131072;
constexpr int   NCOL_ = NVL_ + CAP_;    // 131264
constexpr float THR_  = 0.5f;
constexpr float EPS_  = 1e-8f;

// workspace float offsets
constexpr int WS_SL  = 128;  // 1   global label sum
constexpr int WS_MN  = 160;  // 128 per-row min(sim_m)
constexpr int WS_MX  = 288;  // 128 per-row max(sim_m)
constexpr int WS_SS  = 416;  // 128 per-row sum(sim_m + 1)
constexpr int WS_SSL = 544;  // 128 per-row sum((sim_m + 1)*label)
constexpr int WS_S0  = 672;  // 128 per-row sum(sim where selected)
constexpr int WS_CNT = 800;  // 128 per-row count(selected)

constexpr int TN    = 128;   // columns per block
constexpr int BK    = 64;    // K tile
constexpr int PITCH = 72;    // LDS pitch in bf16 (144 B = 9*16B: aligned b128, conflict-floor)
}

using bf16x8 = __attribute__((ext_vector_type(8))) short;
using f32x4  = __attribute__((ext_vector_type(4))) float;

__device__ inline void atomicMinF(float* addr, float v) {
    if (v >= 0.f) atomicMin((int*)addr, __float_as_int(v));
    else          atomicMax((unsigned int*)addr, __float_as_uint(v));
}
__device__ inline void atomicMaxF(float* addr, float v) {
    if (v >= 0.f) atomicMax((int*)addr, __float_as_int(v));
    else          atomicMin((unsigned int*)addr, __float_as_uint(v));
}
// pack two f32 -> two bf16 (RNE) in one u32
__device__ inline unsigned pk2bf(float a, float b) {
    unsigned ua = __float_as_uint(a), ub = __float_as_uint(b);
    ua += 0x7fffu + ((ua >> 16) & 1u);
    ub += 0x7fffu + ((ub >> 16) & 1u);
    return (ua >> 16) | (ub & 0xffff0000u);
}

// ---------------- kernel 0: init accumulators ----------------
__global__ void lpe_init(float* ws) {
    int t = threadIdx.x;
    if (t < NQ_) {
        ws[WS_MN + t]  = INFINITY;
        ws[WS_MX + t]  = -INFINITY;
        ws[WS_SS + t]  = 0.f;
        ws[WS_SSL + t] = 0.f;
        ws[WS_S0 + t]  = 0.f;
        ws[WS_CNT + t] = 0.f;
    }
    if (t == 0) ws[WS_SL] = 0.f;
}

// ---------------- kernel 1: global label sum ----------------
__global__ void lpe_prep(const float* __restrict__ itm,
                         const float* __restrict__ expl,
                         float* ws) {
    __shared__ float red[256];
    int t = threadIdx.x;
    int idx = blockIdx.x * 256 + t;
    float s = 0.f;
    for (int j = idx; j < NCOL_; j += 256 * 256)
        s += (j < NVL_) ? itm[j] : expl[j - NVL_];
    red[t] = s; __syncthreads();
    for (int o = 128; o > 0; o >>= 1) { if (t < o) red[t] += red[t + o]; __syncthreads(); }
    if (t == 0) atomicAdd(ws + WS_SL, red[0]);
}

// ---------------- kernel 2: bf16-MFMA fused GEMM + stats ----------------
__global__ __launch_bounds__(256, 2) void lpe_main(
        const float* __restrict__ vl, const float* __restrict__ score,
        const float* __restrict__ itm, const float* __restrict__ queue,
        const float* __restrict__ expl, const float* __restrict__ W,
        const float* __restrict__ bvec, float* ws) {
    __shared__ unsigned short As[NQ_][PITCH];   // bf16 A tile [row][k]
    __shared__ unsigned short Bsh[TN][PITCH];   // bf16 B tile [col][k]
    __shared__ float colnorm[TN], colscore[TN], collab_s[TN];
    __shared__ float rowscore[NQ_], qn_s[NQ_];
    __shared__ float ls_mn[NQ_], ls_mx[NQ_], ls_ss[NQ_], ls_ssl[NQ_], ls_s0[NQ_], ls_cnt[NQ_];

    const int t    = threadIdx.x;
    const int lane = t & 63;
    const int wv   = t >> 6;           // wave 0..3
    const int wm   = wv >> 1, wn = wv & 1;
    const int fr   = lane & 15;        // frag row/col
    const int fq   = lane >> 4;        // frag quarter
    const int col0 = blockIdx.x * TN;

    if (t < NQ_) {
        rowscore[t] = score[BS_ + t];
        ls_mn[t] = INFINITY; ls_mx[t] = -INFINITY;
        ls_ss[t] = 0.f; ls_ssl[t] = 0.f; ls_s0[t] = 0.f; ls_cnt[t] = 0.f;
        int j = col0 + t;
        collab_s[t] = (j < NCOL_) ? ((j < NVL_) ? itm[j] : expl[j - NVL_]) : 0.f;
    }
    const float b0 = bvec[0], b1 = bvec[1];

    // staging assignment: column/row c = t>>1, k-half kh
    const int  c  = t >> 1;
    const int  kh = (t & 1) * 32;
    const int  jcol   = col0 + c;
    const bool jvalid = jcol < NCOL_;
    const float* bsrc = (jcol < NVL_) ? (vl + (size_t)jcol * D_)
                                      : (queue + (size_t)(jcol - NVL_) * D_);
    const float* asrc = vl + (size_t)(BS_ + c) * D_;

    float a_ss = 0.f, c_ss = 0.f, c_z0 = 0.f, c_z1 = 0.f;

    f32x4 acc[4][4];
#pragma unroll
    for (int m = 0; m < 4; ++m)
#pragma unroll
        for (int n = 0; n < 4; ++n) acc[m][n] = (f32x4){0.f, 0.f, 0.f, 0.f};

    for (int k0 = 0; k0 < D_; k0 += BK) {
        __syncthreads();
        // stage A (queries): fp32 -> stats -> bf16 LDS
#pragma unroll
        for (int i = 0; i < 8; ++i) {
            const float4 v = *(const float4*)(asrc + k0 + kh + i * 4);
            a_ss += v.x * v.x + v.y * v.y + v.z * v.z + v.w * v.w;
            uint2 p; p.x = pk2bf(v.x, v.y); p.y = pk2bf(v.z, v.w);
            *(uint2*)&As[c][kh + i * 4] = p;
        }
        // stage B (columns): fp32 -> stats (norm + W-projection) -> bf16 LDS
#pragma unroll
        for (int i = 0; i < 8; ++i) {
            float4 v = make_float4(0.f, 0.f, 0.f, 0.f);
            if (jvalid) v = *(const float4*)(bsrc + k0 + kh + i * 4);
            const int k = k0 + kh + i * 4;
            const float4 w01 = *(const float4*)(W + (size_t)k * 2);
            const float4 w23 = *(const float4*)(W + (size_t)k * 2 + 4);
            c_ss += v.x * v.x + v.y * v.y + v.z * v.z + v.w * v.w;
            c_z0 += v.x * w01.x + v.y * w01.z + v.z * w23.x + v.w * w23.z;
            c_z1 += v.x * w01.y + v.y * w01.w + v.z * w23.y + v.w * w23.w;
            uint2 p; p.x = pk2bf(v.x, v.y); p.y = pk2bf(v.z, v.w);
            *(uint2*)&Bsh[c][kh + i * 4] = p;
        }
        __syncthreads();
        // MFMA: each wave computes 64x64, 4x4 frags of 16x16, two 32-k steps
#pragma unroll
        for (int kk = 0; kk < 2; ++kk) {
            bf16x8 af[4], bfr[4];
#pragma unroll
            for (int m = 0; m < 4; ++m)
                af[m] = *(const bf16x8*)&As[wm * 64 + m * 16 + fr][kk * 32 + fq * 8];
#pragma unroll
            for (int n = 0; n < 4; ++n)
                bfr[n] = *(const bf16x8*)&Bsh[wn * 64 + n * 16 + fr][kk * 32 + fq * 8];
#pragma unroll
            for (int m = 0; m < 4; ++m)
#pragma unroll
                for (int n = 0; n < 4; ++n)
                    acc[m][n] = __builtin_amdgcn_mfma_f32_16x16x32_bf16(
                        af[m], bfr[n], acc[m][n], 0, 0, 0);
        }
    }

    // finalize per-row/per-column stats (pair reduce t, t^1)
    a_ss += __shfl_xor(a_ss, 1);
    c_ss += __shfl_xor(c_ss, 1);
    c_z0 += __shfl_xor(c_z0, 1);
    c_z1 += __shfl_xor(c_z1, 1);
    if ((t & 1) == 0) {
        qn_s[c]    = sqrtf(a_ss);
        colnorm[c] = sqrtf(c_ss);
        float sc;
        if (jcol < NVL_) sc = score[jcol];
        else { float z = (c_z1 + b1) - (c_z0 + b0); sc = 1.f / (1.f + expf(-z)); }
        colscore[c] = sc;
    }
    __syncthreads();

    // epilogue: per-row online reductions over this block's 128 columns
#pragma unroll
    for (int m = 0; m < 4; ++m) {
#pragma unroll
        for (int j = 0; j < 4; ++j) {
            const int   r  = wm * 64 + m * 16 + fq * 4 + j;
            const float qn = qn_s[r];
            const float rs = rowscore[r];
            float mn = INFINITY, mx = -INFINITY, ss = 0.f, ssl = 0.f, s0 = 0.f, cnt = 0.f;
#pragma unroll
            for (int n = 0; n < 4; ++n) {
                const int cc = wn * 64 + n * 16 + fr;
                const float cosv = acc[m][n][j] / fmaxf(qn * colnorm[cc], EPS_);
                float dd = colscore[cc] - rs; dd *= dd;
                const float sim = cosv * (1.f - dd);
                const bool  sel = (cosv >= THR_);
                const float sim_m = sel ? sim : -1.f;
                mn = fminf(mn, sim_m);
                mx = fmaxf(mx, sim_m);
                ss  += sim_m + 1.f;                 // OOB cols contribute exactly 0
                ssl += (sim_m + 1.f) * collab_s[cc];
                if (sel) { s0 += sim; cnt += 1.f; }
            }
#pragma unroll
            for (int off = 1; off < 16; off <<= 1) {
                mn  = fminf(mn, __shfl_xor(mn, off));
                mx  = fmaxf(mx, __shfl_xor(mx, off));
                ss  += __shfl_xor(ss, off);
                ssl += __shfl_xor(ssl, off);
                s0  += __shfl_xor(s0, off);
                cnt += __shfl_xor(cnt, off);
            }
            if (fr == 0) {
                atomicMinF(&ls_mn[r], mn);
                atomicMaxF(&ls_mx[r], mx);
                atomicAdd(&ls_ss[r],  ss);
                atomicAdd(&ls_ssl[r], ssl);
                atomicAdd(&ls_s0[r],  s0);
                atomicAdd(&ls_cnt[r], cnt);
            }
        }
    }
    __syncthreads();
    if (t < NQ_) {
        atomicMinF(ws + WS_MN + t, ls_mn[t]);
        atomicMaxF(ws + WS_MX + t, ls_mx[t]);
        atomicAdd(ws + WS_SS + t,  ls_ss[t]);
        atomicAdd(ws + WS_SSL + t, ls_ssl[t]);
        atomicAdd(ws + WS_S0 + t,  ls_s0[t]);
        atomicAdd(ws + WS_CNT + t, ls_cnt[t]);
    }
}

// ---------------- kernel 3: finalize outputs ----------------
__global__ void lpe_final(float* out, const float* ws) {
    int t = threadIdx.x;
    if (t < BS_) {
        out[t] = 1.f;            // exp_itm_label[:64]
        out[192 + t] = 1.f;      // exp_wo_alter_label[:64]
        out[385 + t] = 0.f;      // weights[:64]
    }
    if (t == 0) out[384] = 1.0f; // gamma = 131264/131264
    if (t >= BS_ && t < NVL_) {
        int i = t - BS_;
        float mn   = ws[WS_MN + i],  mx   = ws[WS_MX + i];
        float ssP  = ws[WS_SS + i],  sslP = ws[WS_SSL + i];
        float s0   = ws[WS_S0 + i],  cnt  = ws[WS_CNT + i];
        float Sl   = ws[WS_SL];
        float denomA = mx - mn + 1e-8f;
        float shift  = mn + 1.f;            // == 0 when min is the -1 sentinel
        float sumd = (ssP - (float)NCOL_ * shift) / denomA;
        float num  = (sslP - shift * Sl) / denomA;
        float wo   = num / (sumd + 1e-8f);
        float alt  = fmaxf(wo, 0.f);
        float w    = (cnt != 0.f) ? s0 / fmaxf(cnt, 1.f) : 0.f;
        float wt   = fmaxf(w - THR_, 0.f) / (1.f - THR_);
        out[BS_ + i] = alt;          // exp_itm_label[64:]
        out[192 + BS_ + i] = wo;     // exp_wo_alter_label[64:]
        out[385 + BS_ + i] = wt;     // weights[64:]
    }
}

extern "C" void kernel_launch(void* const* d_in, const int* in_sizes, int n_in,
                              void* d_out, int out_size, void* d_ws, size_t ws_size,
                              hipStream_t stream) {
    const float* vl    = (const float*)d_in[0];
    const float* score = (const float*)d_in[1];
    const float* itm   = (const float*)d_in[2];
    const float* queue = (const float*)d_in[3];
    const float* expl  = (const float*)d_in[4];
    const float* W     = (const float*)d_in[5];
    const float* b     = (const float*)d_in[6];
    float* out = (float*)d_out;
    float* ws  = (float*)d_ws;

    lpe_init<<<1, 256, 0, stream>>>(ws);
    lpe_prep<<<256, 256, 0, stream>>>(itm, expl, ws);
    const int nblk = (NCOL_ + TN - 1) / TN;   // 1026
    lpe_main<<<nblk, 256, 0, stream>>>(vl, score, itm, queue, expl, W, b, ws);
    lpe_final<<<1, 256, 0, stream>>>(out, ws);
}